// Round 17
// baseline (373.512 us; speedup 1.0000x reference)
//
#include <hip/hip_runtime.h>

typedef _Float16 half8 __attribute__((ext_vector_type(8)));
typedef float f32x4 __attribute__((ext_vector_type(4)));
typedef float f32x16 __attribute__((ext_vector_type(16)));

__device__ __forceinline__ unsigned short f2h(float f) {
    _Float16 h = (_Float16)f;
    return __builtin_bit_cast(unsigned short, h);
}
__device__ __forceinline__ float h2f(unsigned short u) {
    return (float)__builtin_bit_cast(_Float16, u);
}

// async global->LDS, 16 B per lane; LDS dest linear (base + lane*16)
__device__ __forceinline__ void lds_load16(const uint4* g, uint4* l) {
    __builtin_amdgcn_global_load_lds(
        (const __attribute__((address_space(1))) unsigned int*)g,
        (__attribute__((address_space(3))) unsigned int*)l, 16, 0, 0);
}

// ---- merged weight prep: 11 conv layers + fc transpose + 1x1 fp16 ----
struct PrepArgs {
    const float* src[13];
    unsigned dstOff[13];
    int Cout[13], Cin[13];
    unsigned off[14];
};

__global__ void prep_all_k(PrepArgs a, char* __restrict__ WT)
{
    unsigned t = blockIdx.x * 256 + threadIdx.x;
    if (t >= a.off[13]) return;
    int l = 0;
    while (t >= a.off[l + 1]) ++l;
    unsigned e = t - a.off[l];
    if (l < 11) {
        int j = e & 7; unsigned r = e >> 3;
        const int Cout = a.Cout[l], Cin = a.Cin[l];
        int co = r % Cout; r /= Cout;
        int oct = r & 3; r >>= 2;
        int pos = r % 9; int ck = r / 9;
        int ci = ck * 32 + oct * 8 + j;
        ((unsigned short*)(WT + a.dstOff[l]))[e] =
            f2h(a.src[l][((size_t)co * Cin + ci) * 9 + pos]);
    } else if (l == 11) {
        int k = e >> 9, ff = e & 511;
        ((float*)(WT + a.dstOff[l]))[e] = a.src[l][ff * 49 + k];
    } else {
        int j = e & 7, co = (e >> 3) & 31, koct = e >> 8;
        ((unsigned short*)(WT + a.dstOff[l]))[e] =
            f2h(a.src[l][co * 32 + koct * 8 + j]);
    }
}

// ---- MFMA conv3x3 SAME, NHWC fp16, fp32 accum; row-reuse B loop ----
// DB=1: double-buffered LDS; next chunk's global_load_lds issued before compute
// (latency hides under MFMAs; __syncthreads provides the vmcnt(0) drain).
// POOL=1: fused 2x2 maxpool second output.
template<int BM, int TW, int TH, int LW, int UP, int POOL, int DB>
__global__ __launch_bounds__(256, 2) void convm5_k(
    const uint4* __restrict__ in1, int C1g,
    const uint4* __restrict__ in2, int C2g,
    const uint4* __restrict__ wt,
    const float* __restrict__ bias,
    unsigned short* __restrict__ out,
    int Cout, int relu, const uint4* __restrict__ zp,
    unsigned short* __restrict__ pout)
{
    constexpr int NM = BM / 16;
    constexpr int NN = (TW * TH) / 64;
    constexpr int CG = TW / 16;
    constexpr int RQ = NN / CG;
    static_assert(RQ == 2, "row-reuse layout needs 2 rows/wave");
    constexpr int Wf = 1 << LW, Hf = Wf;
    constexpr int WC = TW + 2, HR = TH + 2;
    constexpr int IN_GR = 4 * HR * WC;
    constexpr int WT_GR = 36 * BM;
    constexpr int CHUNK = IN_GR + WT_GR;
    constexpr int LTW = (TW == 64) ? 6 : 5;
    constexpr int sH = UP ? (Hf >> 1) : Hf;
    constexpr int sW = UP ? (Wf >> 1) : Wf;
    constexpr int NBUF = DB ? 2 : 1;
    __shared__ uint4 smem[NBUF][CHUNK];

    const int tid = threadIdx.x;
    const int lane = tid & 63, wv = tid >> 6;
    const int ng = Cout / BM;
    const int b = blockIdx.z / ng, cg = blockIdx.z % ng;
    const int x0 = blockIdx.x * TW, y0 = blockIdx.y * TH;
    const int NCK = (C1g + C2g) / 4;

    f32x4 acc[NM][NN];
#pragma unroll
    for (int m = 0; m < NM; ++m)
#pragma unroll
        for (int n = 0; n < NN; ++n) acc[m][n] = (f32x4){0.f, 0.f, 0.f, 0.f};

    const int l15 = lane & 15, l4 = lane >> 4;
    const int laneB = l4 * HR * WC + l15;
    const int laneA = l4 * BM + l15;

    auto stage = [&](int ck, int par) {
        const uint4* src; int cg0, srcCg;
        if (ck * 4 < C1g) { src = in1; cg0 = ck * 4; srcCg = C1g; }
        else              { src = in2; cg0 = ck * 4 - C1g; srcCg = C2g; }
        for (int i = tid; i < IN_GR; i += 256) {
            int oct = i / (HR * WC);
            int rem = i - oct * (HR * WC);
            int row = rem / WC;
            int col = rem - row * WC;
            int gy = y0 + row - 1, gx = x0 + col - 1;
            int sy = UP ? (gy >> 1) : gy, sx = UP ? (gx >> 1) : gx;
            const uint4* ga = ((unsigned)gy < (unsigned)Hf && (unsigned)gx < (unsigned)Wf)
                ? src + ((((size_t)b * sH + sy) * sW + sx) * srcCg + cg0 + oct)
                : zp + (i & 63);
            lds_load16(ga, &smem[par][i]);
        }
        const uint4* wck = wt + (size_t)ck * 36 * Cout + (size_t)cg * BM;
        for (int i = tid; i < WT_GR; i += 256) {
            int seg = i / BM, col = i - seg * BM;
            lds_load16(wck + seg * Cout + col, &smem[par][IN_GR + i]);
        }
    };

    stage(0, 0);
    __syncthreads();
    for (int ck = 0; ck < NCK; ++ck) {
        const int par = DB ? (ck & 1) : 0;
        if (DB && ck + 1 < NCK) stage(ck + 1, par ^ 1);
        const half8* sB = (const half8*)smem[par];
        const half8* sA = (const half8*)(smem[par] + IN_GR);
#pragma unroll
        for (int dc = 0; dc < 3; ++dc) {
            half8 br[RQ + 2][CG];
#pragma unroll
            for (int r = 0; r < RQ + 2; ++r)
#pragma unroll
                for (int c2 = 0; c2 < CG; ++c2)
                    br[r][c2] = sB[(wv * RQ + r) * WC + c2 * 16 + dc + laneB];
#pragma unroll
            for (int dr = 0; dr < 3; ++dr) {
                half8 af[NM];
#pragma unroll
                for (int m = 0; m < NM; ++m)
                    af[m] = sA[(dr * 3 + dc) * 4 * BM + m * 16 + laneA];
#pragma unroll
                for (int m = 0; m < NM; ++m)
#pragma unroll
                    for (int rq = 0; rq < RQ; ++rq)
#pragma unroll
                        for (int c2 = 0; c2 < CG; ++c2)
                            acc[m][rq * CG + c2] = __builtin_amdgcn_mfma_f32_16x16x32_f16(
                                af[m], br[rq + dr][c2], acc[m][rq * CG + c2], 0, 0, 0);
            }
        }
        if (ck + 1 < NCK) {
            if (!DB) { __syncthreads(); stage(ck + 1, 0); }
            __syncthreads();
        }
    }

    // epilogue: bias + relu + NHWC store; POOL: fused 2x2 max
#pragma unroll
    for (int m = 0; m < NM; ++m) {
        const int co0 = cg * BM + m * 16 + l4 * 4;
        const float4 bs = *(const float4*)(bias + co0);
#pragma unroll
        for (int c2 = 0; c2 < CG; ++c2) {
            float pv0, pv1, pv2, pv3;
#pragma unroll
            for (int rq = 0; rq < RQ; ++rq) {
                const int n = rq * CG + c2;
                const int pix = wv * (NN * 16) + n * 16 + l15;
                const int y = y0 + (pix >> LTW), x = x0 + (pix & (TW - 1));
                float v0 = acc[m][n][0] + bs.x;
                float v1 = acc[m][n][1] + bs.y;
                float v2 = acc[m][n][2] + bs.z;
                float v3 = acc[m][n][3] + bs.w;
                if (relu) {
                    v0 = fmaxf(v0, 0.f); v1 = fmaxf(v1, 0.f);
                    v2 = fmaxf(v2, 0.f); v3 = fmaxf(v3, 0.f);
                }
                uint2 pk;
                pk.x = (unsigned)f2h(v0) | ((unsigned)f2h(v1) << 16);
                pk.y = (unsigned)f2h(v2) | ((unsigned)f2h(v3) << 16);
                *(uint2*)(out + (((size_t)b * Hf + y) * Wf + x) * Cout + co0) = pk;
                if (POOL) {
                    if (rq == 0) { pv0 = v0; pv1 = v1; pv2 = v2; pv3 = v3; }
                    else {
                        pv0 = fmaxf(pv0, v0); pv1 = fmaxf(pv1, v1);
                        pv2 = fmaxf(pv2, v2); pv3 = fmaxf(pv3, v3);
                    }
                }
            }
            if (POOL) {
                float q0 = fmaxf(pv0, __shfl_xor(pv0, 1));
                float q1 = fmaxf(pv1, __shfl_xor(pv1, 1));
                float q2 = fmaxf(pv2, __shfl_xor(pv2, 1));
                float q3 = fmaxf(pv3, __shfl_xor(pv3, 1));
                if ((l15 & 1) == 0) {
                    const int xp = (x0 >> 1) + ((c2 * 16 + l15) >> 1);
                    const int yp = (y0 >> 1) + wv;
                    uint2 pk;
                    pk.x = (unsigned)f2h(q0) | ((unsigned)f2h(q1) << 16);
                    pk.y = (unsigned)f2h(q2) | ((unsigned)f2h(q3) << 16);
                    *(uint2*)(pout + (((size_t)b * (Hf >> 1) + yp) * (Wf >> 1) + xp) * Cout + co0) = pk;
                }
            }
        }
    }
}

// ---- first conv 3->32, fp32 direct, NCHW fp32 in -> NHWC fp16 out ----
__global__ __launch_bounds__(256) void conv0_k(
    const float* __restrict__ in, const float* __restrict__ w,
    const float* __restrict__ bias, unsigned short* __restrict__ out)
{
    __shared__ float s_in[3][18][18];
    const int tx = threadIdx.x, ty = threadIdx.y;
    const int tid = ty * 16 + tx;
    const int b = blockIdx.z >> 2;
    const int coBase = (blockIdx.z & 3) * 8;
    const int bx = blockIdx.x * 16, by = blockIdx.y * 16;

    for (int i = tid; i < 3 * 18 * 18; i += 256) {
        int cc = i / 324, r = i % 324;
        int ly = r / 18, lx = r % 18;
        int gy = by + ly - 1, gx = bx + lx - 1;
        float v = 0.f;
        if ((unsigned)gy < 256u && (unsigned)gx < 256u)
            v = in[(((size_t)(b * 3 + cc)) << 16) + (gy << 8) + gx];
        ((float*)s_in)[i] = v;
    }
    __syncthreads();
    float acc[8];
#pragma unroll
    for (int k = 0; k < 8; ++k) acc[k] = 0.f;
    for (int cc = 0; cc < 3; ++cc) {
        float v[9];
#pragma unroll
        for (int dh = 0; dh < 3; ++dh)
#pragma unroll
            for (int dw = 0; dw < 3; ++dw)
                v[dh * 3 + dw] = s_in[cc][ty + dh][tx + dw];
        const float* wp = w + ((size_t)coBase * 3 + cc) * 9;
#pragma unroll
        for (int k = 0; k < 8; ++k) {
            const float* wk = wp + (size_t)k * 27;
            float a = acc[k];
#pragma unroll
            for (int j = 0; j < 9; ++j) a = fmaf(v[j], wk[j], a);
            acc[k] = a;
        }
    }
    const int h = by + ty, ww = bx + tx;
    unsigned short* op = out + (((size_t)(b * 256 + h)) * 256 + ww) * 32 + coBase;
#pragma unroll
    for (int k = 0; k < 8; ++k)
        op[k] = f2h(fmaxf(acc[k] + bias[coBase + k], 0.f));
}

// ---- 1x1 conv 32->32 (MFMA 32x32), NHWC fp16 in -> NCHW fp16 planes ----
__global__ __launch_bounds__(256) void conv1x1f_k(
    const uint4* __restrict__ in, const uint4* __restrict__ w16,
    const float* __restrict__ bias, unsigned short* __restrict__ f)
{
    __shared__ uint4 sIn[1024];
    __shared__ uint4 sW[128];
    __shared__ float sb[32];
    const int tid = threadIdx.x;
    const int lane = tid & 63, wv = tid >> 6;
    const int l31 = lane & 31, l5 = lane >> 5;
    const int y = blockIdx.x, b = blockIdx.y;

    const uint4* ip = in + (((size_t)b * 256 + y) * 256) * 4;
#pragma unroll
    for (int it = 0; it < 4; ++it)
        lds_load16(ip + tid + it * 256, &sIn[tid + it * 256]);
    if (tid < 128) lds_load16(w16 + tid, &sW[tid]);
    if (tid < 32) sb[tid] = bias[tid];
    __syncthreads();

    const half8* hW = (const half8*)sW;
    const half8* hIn = (const half8*)sIn;
    half8 af0 = hW[l5 * 32 + l31];
    half8 af1 = hW[(2 + l5) * 32 + l31];
    unsigned short* fp_ = f + ((size_t)b * 32) * 65536 + (size_t)y * 256;
#pragma unroll
    for (int g = 0; g < 2; ++g) {
        const int p0 = wv * 64 + g * 32;
        half8 bf0 = hIn[(p0 + l31) * 4 + l5];
        half8 bf1 = hIn[(p0 + l31) * 4 + 2 + l5];
        f32x16 acc;
#pragma unroll
        for (int q = 0; q < 16; ++q) acc[q] = 0.f;
        acc = __builtin_amdgcn_mfma_f32_32x32x16_f16(af0, bf0, acc, 0, 0, 0);
        acc = __builtin_amdgcn_mfma_f32_32x32x16_f16(af1, bf1, acc, 0, 0, 0);
#pragma unroll
        for (int r = 0; r < 16; ++r) {
            const int co = (r & 3) + 8 * (r >> 2) + 4 * l5;
            fp_[(size_t)co * 65536 + p0 + l31] = f2h(acc[r] + sb[co]);
        }
    }
}

// ---- global pool pass 1: per-(y-bin, c, b) column sums ----
__global__ __launch_bounds__(256) void gcol_k(
    const unsigned short* __restrict__ f, float* __restrict__ colsumG)
{
    const int ki = blockIdx.x;
    const int c  = blockIdx.y;
    const int b  = blockIdx.z;
    const int x  = threadIdx.x;
    const int sy = (ki * 256) / 7, ey = ((ki + 1) * 256 + 6) / 7;
    const unsigned short* pl = f + (size_t)(b * 32 + c) * 65536;
    float s = 0.f;
    for (int y = sy; y < ey; ++y)
        s += h2f(pl[(size_t)y * 256 + x]);
    colsumG[((size_t)(b * 32 + c) * 7 + ki) * 256 + x] = s;
}

// ---- global pool pass 2: reduce x-ranges -> pooled[b][n<32][49] ----
__global__ __launch_bounds__(64) void gpool2_k(
    const float* __restrict__ colsumG, float* __restrict__ pooled)
{
    const int c = blockIdx.x, b = blockIdx.y;
    const int lane = threadIdx.x;
    if (lane >= 49) return;
    const int ki = lane / 7, kj = lane % 7;
    const int sy = (ki * 256) / 7, ey = ((ki + 1) * 256 + 6) / 7;
    const int sx = (kj * 256) / 7, ex = ((kj + 1) * 256 + 6) / 7;
    const float* cs = colsumG + ((size_t)(b * 32 + c) * 7 + ki) * 256;
    float s = 0.f;
    for (int x = sx; x < ex; ++x) s += cs[x];
    pooled[((size_t)b * 1056 + c) * 49 + lane] = s / (float)((ey - sy) * (ex - sx));
}

// ---- ROI adaptive pool (w,h <= 63): one wave per (b, n>=32) ----
__global__ __launch_bounds__(64) void roi_k(
    const unsigned short* __restrict__ f, const int* __restrict__ rois,
    float* __restrict__ pooled)
{
    __shared__ float colsum[7][64];
    const int n = 32 + blockIdx.x, b = blockIdx.y;
    const int lane = threadIdx.x;
    const int r = (n - 32) >> 5;
    const int c = (n - 32) & 31;
    const int x1 = rois[r * 4 + 0], y1 = rois[r * 4 + 1];
    const int x2 = rois[r * 4 + 2], y2 = rois[r * 4 + 3];
    const int h = y2 - y1, w = x2 - x1;
    const unsigned short* pl = f + (size_t)(b * 32 + c) * 65536;
    if (lane < w) {
        const int x = x1 + lane;
#pragma unroll
        for (int ki = 0; ki < 7; ++ki) {
            const int sy = y1 + (ki * h) / 7, ey = y1 + ((ki + 1) * h + 6) / 7;
            float s = 0.f;
            for (int y = sy; y < ey; ++y)
                s += h2f(pl[(size_t)y * 256 + x]);
            colsum[ki][lane] = s;
        }
    }
    __syncthreads();
    if (lane >= 49) return;
    const int ki = lane / 7, kj = lane % 7;
    const int sy = y1 + (ki * h) / 7, ey = y1 + ((ki + 1) * h + 6) / 7;
    const int sxo = (kj * w) / 7, exo = ((kj + 1) * w + 6) / 7;
    float s = 0.f;
    for (int j = sxo; j < exo; ++j) s += colsum[ki][j];
    pooled[((size_t)b * 1056 + n) * 49 + lane] = s / (float)((ey - sy) * (exo - sxo));
}

// ---- FC: out[b,n,f] = pooled[b,n,:] . fcwT[:,f] + fcb[f] ----
__global__ __launch_bounds__(512) void fc_k(
    const float* __restrict__ pooled, const float* __restrict__ fcwT,
    const float* __restrict__ fcb, float* __restrict__ out)
{
    const int nt = blockIdx.x, b = blockIdx.y;
    const int f = threadIdx.x;
    float wr[49];
#pragma unroll
    for (int k = 0; k < 49; ++k) wr[k] = fcwT[k * 512 + f];
    const float base = fcb[f];
    const float* pr = pooled + ((size_t)b * 1056 + nt * 16) * 49;
    float* op = out + (((size_t)b * 1056 + nt * 16)) * 512 + f;
#pragma unroll
    for (int j = 0; j < 16; ++j) {
        float a = base;
#pragma unroll
        for (int k = 0; k < 49; ++k)
            a = fmaf(pr[j * 49 + k], wr[k], a);
        op[(size_t)j * 512] = a;
    }
}

extern "C" void kernel_launch(void* const* d_in, const int* in_sizes, int n_in,
                              void* d_out, int out_size, void* d_ws, size_t ws_size,
                              hipStream_t stream)
{
    const float* x    = (const float*)d_in[0];
    const int*   rois = (const int*)d_in[1];
    const float* e1w1 = (const float*)d_in[2];
    const float* e1b1 = (const float*)d_in[3];
    const float* e1w2 = (const float*)d_in[4];
    const float* e1b2 = (const float*)d_in[5];
    const float* e2w1 = (const float*)d_in[6];
    const float* e2b1 = (const float*)d_in[7];
    const float* e2w2 = (const float*)d_in[8];
    const float* e2b2 = (const float*)d_in[9];
    const float* bw1  = (const float*)d_in[10];
    const float* bb1  = (const float*)d_in[11];
    const float* bw2  = (const float*)d_in[12];
    const float* bb2  = (const float*)d_in[13];
    const float* u2w  = (const float*)d_in[14];
    const float* u2b  = (const float*)d_in[15];
    const float* d2w1 = (const float*)d_in[16];
    const float* d2b1 = (const float*)d_in[17];
    const float* d2w2 = (const float*)d_in[18];
    const float* d2b2 = (const float*)d_in[19];
    const float* u1w  = (const float*)d_in[20];
    const float* u1b  = (const float*)d_in[21];
    const float* d1w1 = (const float*)d_in[22];
    const float* d1b1 = (const float*)d_in[23];
    const float* d1w2 = (const float*)d_in[24];
    const float* d1b2 = (const float*)d_in[25];
    const float* fw   = (const float*)d_in[26];
    const float* fb   = (const float*)d_in[27];
    const float* fcw  = (const float*)d_in[28];
    const float* fcb  = (const float*)d_in[29];

    // ---- workspace: WT(4MB) A(33.5) D(16.8) E(16.8) B(33.5) C(8.4) F(33.5)
    char* wsb = (char*)d_ws;
    char* WT = wsb;
    char* A  = wsb + 4194304;
    char* D  = A + 33554432;
    char* E  = D + 16777216;
    char* Bb = E + 16777216;
    char* C  = Bb + 33554432;
    char* F  = C + 8388608;
    float* fcwT   = (float*)(WT + 1179648);
    unsigned short* fw16 = (unsigned short*)(WT + 2097152);
    uint4* zp     = (uint4*)(WT + 4194304 - 8192);
    unsigned short* fpl = (unsigned short*)F;
    float* pooled = (float*)C;
    float* colsumG = (float*)(C + 2097152);
    hipMemsetAsync(zp, 0, 8192, stream);

    // ---- merged weight transforms (1 launch) ----
    const float* wsrc[11] = {e1w2, e2w1, e2w2, bw1, bw2, u2w, d2w1, d2w2, u1w, d1w1, d1w2};
    const int wco[11] = {32, 64, 64, 128, 128, 64, 64, 64, 32, 32, 32};
    const int wci[11] = {32, 32, 64, 64, 128, 128, 128, 64, 64, 64, 32};
    size_t woff[11]; size_t o = 0;
    PrepArgs pa;
    unsigned eoff = 0;
    for (int i = 0; i < 11; ++i) {
        woff[i] = o; o += (size_t)wco[i] * wci[i] * 18;
        pa.src[i] = wsrc[i]; pa.dstOff[i] = (unsigned)woff[i];
        pa.Cout[i] = wco[i]; pa.Cin[i] = wci[i];
        pa.off[i] = eoff; eoff += (unsigned)(wco[i] * wci[i] * 9);
    }
    pa.src[11] = fcw; pa.dstOff[11] = 1179648; pa.Cout[11] = 0; pa.Cin[11] = 0;
    pa.off[11] = eoff; eoff += 49 * 512;
    pa.src[12] = fw; pa.dstOff[12] = 2097152; pa.Cout[12] = 0; pa.Cin[12] = 0;
    pa.off[12] = eoff; eoff += 4096;
    pa.off[13] = eoff;
    hipLaunchKernelGGL(prep_all_k, dim3((eoff + 255) / 256), dim3(256), 0, stream, pa, WT);
    auto WP = [&](int i) { return (const uint4*)(WT + woff[i]); };

    // Configs: 256²: BM32 TW32 LW8 (S: 39.25 KB 4blk/CU; D: 80.4 KB 2blk/CU)
    //          128²: S=BM64 (58.6 KB 2blk/CU); D=BM32 dbuf
    //           64²: BM32 dbuf
    #define CV1S(i1,C1,i2,C2,wi,bs,ot,Cout,up,rl,pl,po) \
        hipLaunchKernelGGL((convm5_k<32,32,8,8,up,pl,0>), dim3(8,32,8*((Cout)/32)), dim3(256), 0, stream, \
            (const uint4*)(i1), (C1)/8, (const uint4*)(i2), (C2)/8, WP(wi), bs, \
            (unsigned short*)(ot), Cout, rl, zp, (unsigned short*)(po))
    #define CV1D(i1,C1,i2,C2,wi,bs,ot,Cout,up,rl,pl,po) \
        hipLaunchKernelGGL((convm5_k<32,32,8,8,up,pl,1>), dim3(8,32,8*((Cout)/32)), dim3(256), 0, stream, \
            (const uint4*)(i1), (C1)/8, (const uint4*)(i2), (C2)/8, WP(wi), bs, \
            (unsigned short*)(ot), Cout, rl, zp, (unsigned short*)(po))
    #define CV2S(i1,C1,i2,C2,wi,bs,ot,Cout,up,rl,pl,po) \
        hipLaunchKernelGGL((convm5_k<64,32,8,7,up,pl,0>), dim3(4,16,8*((Cout)/64)), dim3(256), 0, stream, \
            (const uint4*)(i1), (C1)/8, (const uint4*)(i2), (C2)/8, WP(wi), bs, \
            (unsigned short*)(ot), Cout, rl, zp, (unsigned short*)(po))
    #define CV2D(i1,C1,i2,C2,wi,bs,ot,Cout,up,rl,pl,po) \
        hipLaunchKernelGGL((convm5_k<32,32,8,7,up,pl,1>), dim3(4,16,8*((Cout)/32)), dim3(256), 0, stream, \
            (const uint4*)(i1), (C1)/8, (const uint4*)(i2), (C2)/8, WP(wi), bs, \
            (unsigned short*)(ot), Cout, rl, zp, (unsigned short*)(po))
    #define CV3D(i1,C1,i2,C2,wi,bs,ot,Cout,up,rl) \
        hipLaunchKernelGGL((convm5_k<32,32,8,6,up,0,1>), dim3(2,8,8*((Cout)/32)), dim3(256), 0, stream, \
            (const uint4*)(i1), (C1)/8, (const uint4*)(i2), (C2)/8, WP(wi), bs, \
            (unsigned short*)(ot), Cout, rl, zp, (unsigned short*)nullptr)

    // encoder
    hipLaunchKernelGGL(conv0_k, dim3(16, 16, 32), dim3(16, 16), 0, stream,
                       x, e1w1, e1b1, (unsigned short*)A);          // e1a -> A
    CV1S(A, 32, nullptr, 0, 0, e1b2, Bb, 32, 0, 1, 1, C);           // e1 -> B, p1 -> C (NCK=1)
    CV2S(C, 32, nullptr, 0, 1, e2b1, A, 64, 0, 1, 0, nullptr);      // e2a -> A (NCK=1)
    CV2D(A, 64, nullptr, 0, 2, e2b2, D, 64, 0, 1, 1, C);            // e2 -> D, p2 -> C (NCK=2)
    // bottleneck
    CV3D(C, 64, nullptr, 0, 3, bb1, E, 128, 0, 1);                  // b1 -> E (NCK=2)
    CV3D(E, 128, nullptr, 0, 4, bb2, A, 128, 0, 1);                 // b2 -> A (NCK=4)
    // decoder level 2
    CV2D(A, 128, nullptr, 0, 5, u2b, E, 64, 1, 1, 0, nullptr);      // u2 -> E (NCK=4)
    CV2D(E, 64, D, 64, 6, d2b1, A, 64, 0, 1, 0, nullptr);           // d2a -> A (NCK=4)
    CV2D(A, 64, nullptr, 0, 7, d2b2, D, 64, 0, 1, 0, nullptr);      // d2 -> D (NCK=2)
    // decoder level 1
    CV1D(D, 64, nullptr, 0, 8, u1b, A, 32, 1, 1, 0, nullptr);       // u1 -> A (NCK=2)
    CV1D(A, 32, Bb, 32, 9, d1b1, D, 32, 0, 1, 0, nullptr);          // d1a -> D+E (NCK=2)
    CV1S(D, 32, nullptr, 0, 10, d1b2, Bb, 32, 0, 1, 0, nullptr);    // d1 -> B (NCK=1)
    // 1x1 conv (MFMA) -> NCHW fp16 planes
    hipLaunchKernelGGL(conv1x1f_k, dim3(256, 8), dim3(256), 0, stream,
                       (const uint4*)Bb, (const uint4*)fw16, fb, fpl);
    // pooling + FC
    hipLaunchKernelGGL(gcol_k, dim3(7, 32, 8), dim3(256), 0, stream, fpl, colsumG);
    hipLaunchKernelGGL(roi_k, dim3(1024, 8), dim3(64), 0, stream, fpl, rois, pooled);
    hipLaunchKernelGGL(gpool2_k, dim3(32, 8), dim3(64), 0, stream, colsumG, pooled);
    hipLaunchKernelGGL(fc_k, dim3(66, 8), dim3(512), 0, stream,
                       pooled, fcwT, fcb, (float*)d_out);
    #undef CV1S
    #undef CV1D
    #undef CV2S
    #undef CV2D
    #undef CV3D
}

// Round 18
// 353.308 us; speedup vs baseline: 1.0572x; 1.0572x over previous
//
#include <hip/hip_runtime.h>

typedef _Float16 half8 __attribute__((ext_vector_type(8)));
typedef float f32x4 __attribute__((ext_vector_type(4)));
typedef float f32x16 __attribute__((ext_vector_type(16)));

__device__ __forceinline__ unsigned short f2h(float f) {
    _Float16 h = (_Float16)f;
    return __builtin_bit_cast(unsigned short, h);
}
__device__ __forceinline__ float h2f(unsigned short u) {
    return (float)__builtin_bit_cast(_Float16, u);
}

// async global->LDS, 16 B per lane; LDS dest linear (base + lane*16)
__device__ __forceinline__ void lds_load16(const uint4* g, uint4* l) {
    __builtin_amdgcn_global_load_lds(
        (const __attribute__((address_space(1))) unsigned int*)g,
        (__attribute__((address_space(3))) unsigned int*)l, 16, 0, 0);
}

// ---- merged weight prep: 11 conv layers + fc transpose + 1x1 fp16 ----
struct PrepArgs {
    const float* src[13];
    unsigned dstOff[13];   // byte offsets into WT
    int Cout[13], Cin[13];
    unsigned off[14];      // element segment offsets
};

__global__ void prep_all_k(PrepArgs a, char* __restrict__ WT)
{
    unsigned t = blockIdx.x * 256 + threadIdx.x;
    if (t >= a.off[13]) return;
    int l = 0;
    while (t >= a.off[l + 1]) ++l;
    unsigned e = t - a.off[l];
    if (l < 11) {
        int j = e & 7; unsigned r = e >> 3;
        const int Cout = a.Cout[l], Cin = a.Cin[l];
        int co = r % Cout; r /= Cout;
        int oct = r & 3; r >>= 2;
        int pos = r % 9; int ck = r / 9;
        int ci = ck * 32 + oct * 8 + j;
        ((unsigned short*)(WT + a.dstOff[l]))[e] =
            f2h(a.src[l][((size_t)co * Cin + ci) * 9 + pos]);
    } else if (l == 11) {
        int k = e >> 9, ff = e & 511;
        ((float*)(WT + a.dstOff[l]))[e] = a.src[l][ff * 49 + k];
    } else {
        int j = e & 7, co = (e >> 3) & 31, koct = e >> 8;
        ((unsigned short*)(WT + a.dstOff[l]))[e] =
            f2h(a.src[l][co * 32 + koct * 8 + j]);
    }
}

// ---- MFMA conv3x3 SAME, NHWC fp16, fp32 accum; row-reuse B-fragment loop ----
// POOL=1: additionally emit 2x2-maxpooled NHWC fp16 output (layer followed by pool).
template<int BM, int TW, int TH, int LW, int UP, int POOL>
__global__ __launch_bounds__(256, 2) void convm4_k(
    const uint4* __restrict__ in1, int C1g,
    const uint4* __restrict__ in2, int C2g,
    const uint4* __restrict__ wt,
    const float* __restrict__ bias,
    unsigned short* __restrict__ out,
    int Cout, int relu, const uint4* __restrict__ zp,
    unsigned short* __restrict__ pout)
{
    constexpr int NM = BM / 16;
    constexpr int NN = (TW * TH) / 64;
    constexpr int CG = TW / 16;
    constexpr int RQ = NN / CG;
    static_assert(RQ == 2, "row-reuse layout needs 2 rows/wave");
    constexpr int Wf = 1 << LW, Hf = Wf;
    constexpr int WC = TW + 2, HR = TH + 2;
    constexpr int IN_GR = 4 * HR * WC;
    constexpr int LTW = (TW == 64) ? 6 : 5;
    constexpr int sH = UP ? (Hf >> 1) : Hf;
    constexpr int sW = UP ? (Wf >> 1) : Wf;
    __shared__ uint4 smem[IN_GR + 36 * BM];

    const int tid = threadIdx.x;
    const int lane = tid & 63, wv = tid >> 6;
    const int ng = Cout / BM;
    const int b = blockIdx.z / ng, cg = blockIdx.z % ng;
    const int x0 = blockIdx.x * TW, y0 = blockIdx.y * TH;
    const int NCK = (C1g + C2g) / 4;

    f32x4 acc[NM][NN];
#pragma unroll
    for (int m = 0; m < NM; ++m)
#pragma unroll
        for (int n = 0; n < NN; ++n) acc[m][n] = (f32x4){0.f, 0.f, 0.f, 0.f};

    const int l15 = lane & 15, l4 = lane >> 4;
    const int laneB = l4 * HR * WC + l15;
    const int laneA = l4 * BM + l15;

    for (int ck = 0; ck < NCK; ++ck) {
        if (ck) __syncthreads();
        {
            const uint4* src; int cg0, srcCg;
            if (ck * 4 < C1g) { src = in1; cg0 = ck * 4; srcCg = C1g; }
            else              { src = in2; cg0 = ck * 4 - C1g; srcCg = C2g; }
            for (int i = tid; i < IN_GR; i += 256) {
                int oct = i / (HR * WC);
                int rem = i - oct * (HR * WC);
                int row = rem / WC;
                int col = rem - row * WC;
                int gy = y0 + row - 1, gx = x0 + col - 1;
                int sy = UP ? (gy >> 1) : gy, sx = UP ? (gx >> 1) : gx;
                const uint4* ga = ((unsigned)gy < (unsigned)Hf && (unsigned)gx < (unsigned)Wf)
                    ? src + ((((size_t)b * sH + sy) * sW + sx) * srcCg + cg0 + oct)
                    : zp + (i & 63);
                lds_load16(ga, &smem[i]);
            }
        }
        {
            const uint4* wck = wt + (size_t)ck * 36 * Cout + (size_t)cg * BM;
            for (int i = tid; i < 36 * BM; i += 256) {
                int seg = i / BM, col = i - seg * BM;
                lds_load16(wck + seg * Cout + col, &smem[IN_GR + i]);
            }
        }
        __syncthreads();
        const half8* sB = (const half8*)smem;
        const half8* sA = (const half8*)(smem + IN_GR);
#pragma unroll
        for (int dc = 0; dc < 3; ++dc) {
            half8 br[RQ + 2][CG];
#pragma unroll
            for (int r = 0; r < RQ + 2; ++r)
#pragma unroll
                for (int c2 = 0; c2 < CG; ++c2)
                    br[r][c2] = sB[(wv * RQ + r) * WC + c2 * 16 + dc + laneB];
#pragma unroll
            for (int dr = 0; dr < 3; ++dr) {
                half8 af[NM];
#pragma unroll
                for (int m = 0; m < NM; ++m)
                    af[m] = sA[(dr * 3 + dc) * 4 * BM + m * 16 + laneA];
#pragma unroll
                for (int m = 0; m < NM; ++m)
#pragma unroll
                    for (int rq = 0; rq < RQ; ++rq)
#pragma unroll
                        for (int c2 = 0; c2 < CG; ++c2)
                            acc[m][rq * CG + c2] = __builtin_amdgcn_mfma_f32_16x16x32_f16(
                                af[m], br[rq + dr][c2], acc[m][rq * CG + c2], 0, 0, 0);
            }
        }
    }

    // epilogue: bias + relu + NHWC store; POOL: fused 2x2 max (rows = rq pair,
    // x-partner = lane^1; f2h monotone so pool-then-round == round-then-pool)
#pragma unroll
    for (int m = 0; m < NM; ++m) {
        const int co0 = cg * BM + m * 16 + l4 * 4;
        const float4 bs = *(const float4*)(bias + co0);
#pragma unroll
        for (int c2 = 0; c2 < CG; ++c2) {
            float pv0, pv1, pv2, pv3;
#pragma unroll
            for (int rq = 0; rq < RQ; ++rq) {
                const int n = rq * CG + c2;
                const int pix = wv * (NN * 16) + n * 16 + l15;
                const int y = y0 + (pix >> LTW), x = x0 + (pix & (TW - 1));
                float v0 = acc[m][n][0] + bs.x;
                float v1 = acc[m][n][1] + bs.y;
                float v2 = acc[m][n][2] + bs.z;
                float v3 = acc[m][n][3] + bs.w;
                if (relu) {
                    v0 = fmaxf(v0, 0.f); v1 = fmaxf(v1, 0.f);
                    v2 = fmaxf(v2, 0.f); v3 = fmaxf(v3, 0.f);
                }
                uint2 pk;
                pk.x = (unsigned)f2h(v0) | ((unsigned)f2h(v1) << 16);
                pk.y = (unsigned)f2h(v2) | ((unsigned)f2h(v3) << 16);
                *(uint2*)(out + (((size_t)b * Hf + y) * Wf + x) * Cout + co0) = pk;
                if (POOL) {
                    if (rq == 0) { pv0 = v0; pv1 = v1; pv2 = v2; pv3 = v3; }
                    else {
                        pv0 = fmaxf(pv0, v0); pv1 = fmaxf(pv1, v1);
                        pv2 = fmaxf(pv2, v2); pv3 = fmaxf(pv3, v3);
                    }
                }
            }
            if (POOL) {
                float q0 = fmaxf(pv0, __shfl_xor(pv0, 1));
                float q1 = fmaxf(pv1, __shfl_xor(pv1, 1));
                float q2 = fmaxf(pv2, __shfl_xor(pv2, 1));
                float q3 = fmaxf(pv3, __shfl_xor(pv3, 1));
                if ((l15 & 1) == 0) {
                    const int xp = (x0 >> 1) + ((c2 * 16 + l15) >> 1);
                    const int yp = (y0 >> 1) + wv;
                    uint2 pk;
                    pk.x = (unsigned)f2h(q0) | ((unsigned)f2h(q1) << 16);
                    pk.y = (unsigned)f2h(q2) | ((unsigned)f2h(q3) << 16);
                    *(uint2*)(pout + (((size_t)b * (Hf >> 1) + yp) * (Wf >> 1) + xp) * Cout + co0) = pk;
                }
            }
        }
    }
}

// ---- first conv 3->32, fp32 direct, NCHW fp32 in -> NHWC fp16 out ----
__global__ __launch_bounds__(256) void conv0_k(
    const float* __restrict__ in, const float* __restrict__ w,
    const float* __restrict__ bias, unsigned short* __restrict__ out)
{
    __shared__ float s_in[3][18][18];
    const int tx = threadIdx.x, ty = threadIdx.y;
    const int tid = ty * 16 + tx;
    const int b = blockIdx.z >> 2;
    const int coBase = (blockIdx.z & 3) * 8;
    const int bx = blockIdx.x * 16, by = blockIdx.y * 16;

    for (int i = tid; i < 3 * 18 * 18; i += 256) {
        int cc = i / 324, r = i % 324;
        int ly = r / 18, lx = r % 18;
        int gy = by + ly - 1, gx = bx + lx - 1;
        float v = 0.f;
        if ((unsigned)gy < 256u && (unsigned)gx < 256u)
            v = in[(((size_t)(b * 3 + cc)) << 16) + (gy << 8) + gx];
        ((float*)s_in)[i] = v;
    }
    __syncthreads();
    float acc[8];
#pragma unroll
    for (int k = 0; k < 8; ++k) acc[k] = 0.f;
    for (int cc = 0; cc < 3; ++cc) {
        float v[9];
#pragma unroll
        for (int dh = 0; dh < 3; ++dh)
#pragma unroll
            for (int dw = 0; dw < 3; ++dw)
                v[dh * 3 + dw] = s_in[cc][ty + dh][tx + dw];
        const float* wp = w + ((size_t)coBase * 3 + cc) * 9;
#pragma unroll
        for (int k = 0; k < 8; ++k) {
            const float* wk = wp + (size_t)k * 27;
            float a = acc[k];
#pragma unroll
            for (int j = 0; j < 9; ++j) a = fmaf(v[j], wk[j], a);
            acc[k] = a;
        }
    }
    const int h = by + ty, ww = bx + tx;
    unsigned short* op = out + (((size_t)(b * 256 + h)) * 256 + ww) * 32 + coBase;
#pragma unroll
    for (int k = 0; k < 8; ++k)
        op[k] = f2h(fmaxf(acc[k] + bias[coBase + k], 0.f));
}

// ---- 1x1 conv 32->32 (MFMA 32x32), NHWC fp16 in -> NCHW fp16 planes ----
__global__ __launch_bounds__(256) void conv1x1f_k(
    const uint4* __restrict__ in, const uint4* __restrict__ w16,
    const float* __restrict__ bias, unsigned short* __restrict__ f)
{
    __shared__ uint4 sIn[1024];     // [px][oct]
    __shared__ uint4 sW[128];       // [koct][co]
    __shared__ float sb[32];
    const int tid = threadIdx.x;
    const int lane = tid & 63, wv = tid >> 6;
    const int l31 = lane & 31, l5 = lane >> 5;
    const int y = blockIdx.x, b = blockIdx.y;

    const uint4* ip = in + (((size_t)b * 256 + y) * 256) * 4;
#pragma unroll
    for (int it = 0; it < 4; ++it)
        lds_load16(ip + tid + it * 256, &sIn[tid + it * 256]);
    if (tid < 128) lds_load16(w16 + tid, &sW[tid]);
    if (tid < 32) sb[tid] = bias[tid];
    __syncthreads();

    const half8* hW = (const half8*)sW;
    const half8* hIn = (const half8*)sIn;
    half8 af0 = hW[l5 * 32 + l31];
    half8 af1 = hW[(2 + l5) * 32 + l31];
    unsigned short* fp_ = f + ((size_t)b * 32) * 65536 + (size_t)y * 256;
#pragma unroll
    for (int g = 0; g < 2; ++g) {
        const int p0 = wv * 64 + g * 32;
        half8 bf0 = hIn[(p0 + l31) * 4 + l5];
        half8 bf1 = hIn[(p0 + l31) * 4 + 2 + l5];
        f32x16 acc;
#pragma unroll
        for (int q = 0; q < 16; ++q) acc[q] = 0.f;
        acc = __builtin_amdgcn_mfma_f32_32x32x16_f16(af0, bf0, acc, 0, 0, 0);
        acc = __builtin_amdgcn_mfma_f32_32x32x16_f16(af1, bf1, acc, 0, 0, 0);
#pragma unroll
        for (int r = 0; r < 16; ++r) {
            const int co = (r & 3) + 8 * (r >> 2) + 4 * l5;
            fp_[(size_t)co * 65536 + p0 + l31] = f2h(acc[r] + sb[co]);
        }
    }
}

// ---- global pool pass 1: per-(y-bin, c, b) column sums; thread = column ----
__global__ __launch_bounds__(256) void gcol_k(
    const unsigned short* __restrict__ f, float* __restrict__ colsumG)
{
    const int ki = blockIdx.x;      // 0..6
    const int c  = blockIdx.y;      // 0..31
    const int b  = blockIdx.z;      // 0..7
    const int x  = threadIdx.x;     // 0..255
    const int sy = (ki * 256) / 7, ey = ((ki + 1) * 256 + 6) / 7;
    const unsigned short* pl = f + (size_t)(b * 32 + c) * 65536;
    float s = 0.f;
    for (int y = sy; y < ey; ++y)
        s += h2f(pl[(size_t)y * 256 + x]);
    colsumG[((size_t)(b * 32 + c) * 7 + ki) * 256 + x] = s;
}

// ---- global pool pass 2: reduce x-ranges -> pooled[b][n<32][49] ----
__global__ __launch_bounds__(64) void gpool2_k(
    const float* __restrict__ colsumG, float* __restrict__ pooled)
{
    const int c = blockIdx.x, b = blockIdx.y;
    const int lane = threadIdx.x;
    if (lane >= 49) return;
    const int ki = lane / 7, kj = lane % 7;
    const int sy = (ki * 256) / 7, ey = ((ki + 1) * 256 + 6) / 7;
    const int sx = (kj * 256) / 7, ex = ((kj + 1) * 256 + 6) / 7;
    const float* cs = colsumG + ((size_t)(b * 32 + c) * 7 + ki) * 256;
    float s = 0.f;
    for (int x = sx; x < ex; ++x) s += cs[x];
    pooled[((size_t)b * 1056 + c) * 49 + lane] = s / (float)((ey - sy) * (ex - sx));
}

// ---- ROI adaptive pool (w,h <= 63): one wave per (b, n>=32) ----
__global__ __launch_bounds__(64) void roi_k(
    const unsigned short* __restrict__ f, const int* __restrict__ rois,
    float* __restrict__ pooled)
{
    __shared__ float colsum[7][64];
    const int n = 32 + blockIdx.x, b = blockIdx.y;
    const int lane = threadIdx.x;
    const int r = (n - 32) >> 5;
    const int c = (n - 32) & 31;
    const int x1 = rois[r * 4 + 0], y1 = rois[r * 4 + 1];
    const int x2 = rois[r * 4 + 2], y2 = rois[r * 4 + 3];
    const int h = y2 - y1, w = x2 - x1;
    const unsigned short* pl = f + (size_t)(b * 32 + c) * 65536;
    if (lane < w) {
        const int x = x1 + lane;
#pragma unroll
        for (int ki = 0; ki < 7; ++ki) {
            const int sy = y1 + (ki * h) / 7, ey = y1 + ((ki + 1) * h + 6) / 7;
            float s = 0.f;
            for (int y = sy; y < ey; ++y)
                s += h2f(pl[(size_t)y * 256 + x]);
            colsum[ki][lane] = s;
        }
    }
    __syncthreads();
    if (lane >= 49) return;
    const int ki = lane / 7, kj = lane % 7;
    const int sy = y1 + (ki * h) / 7, ey = y1 + ((ki + 1) * h + 6) / 7;
    const int sxo = (kj * w) / 7, exo = ((kj + 1) * w + 6) / 7;
    float s = 0.f;
    for (int j = sxo; j < exo; ++j) s += colsum[ki][j];
    pooled[((size_t)b * 1056 + n) * 49 + lane] = s / (float)((ey - sy) * (exo - sxo));
}

// ---- FC: out[b,n,f] = pooled[b,n,:] . fcwT[:,f] + fcb[f] ----
__global__ __launch_bounds__(512) void fc_k(
    const float* __restrict__ pooled, const float* __restrict__ fcwT,
    const float* __restrict__ fcb, float* __restrict__ out)
{
    const int nt = blockIdx.x, b = blockIdx.y;
    const int f = threadIdx.x;
    float wr[49];
#pragma unroll
    for (int k = 0; k < 49; ++k) wr[k] = fcwT[k * 512 + f];
    const float base = fcb[f];
    const float* pr = pooled + ((size_t)b * 1056 + nt * 16) * 49;
    float* op = out + (((size_t)b * 1056 + nt * 16)) * 512 + f;
#pragma unroll
    for (int j = 0; j < 16; ++j) {
        float a = base;
#pragma unroll
        for (int k = 0; k < 49; ++k)
            a = fmaf(pr[j * 49 + k], wr[k], a);
        op[(size_t)j * 512] = a;
    }
}

extern "C" void kernel_launch(void* const* d_in, const int* in_sizes, int n_in,
                              void* d_out, int out_size, void* d_ws, size_t ws_size,
                              hipStream_t stream)
{
    const float* x    = (const float*)d_in[0];
    const int*   rois = (const int*)d_in[1];
    const float* e1w1 = (const float*)d_in[2];
    const float* e1b1 = (const float*)d_in[3];
    const float* e1w2 = (const float*)d_in[4];
    const float* e1b2 = (const float*)d_in[5];
    const float* e2w1 = (const float*)d_in[6];
    const float* e2b1 = (const float*)d_in[7];
    const float* e2w2 = (const float*)d_in[8];
    const float* e2b2 = (const float*)d_in[9];
    const float* bw1  = (const float*)d_in[10];
    const float* bb1  = (const float*)d_in[11];
    const float* bw2  = (const float*)d_in[12];
    const float* bb2  = (const float*)d_in[13];
    const float* u2w  = (const float*)d_in[14];
    const float* u2b  = (const float*)d_in[15];
    const float* d2w1 = (const float*)d_in[16];
    const float* d2b1 = (const float*)d_in[17];
    const float* d2w2 = (const float*)d_in[18];
    const float* d2b2 = (const float*)d_in[19];
    const float* u1w  = (const float*)d_in[20];
    const float* u1b  = (const float*)d_in[21];
    const float* d1w1 = (const float*)d_in[22];
    const float* d1b1 = (const float*)d_in[23];
    const float* d1w2 = (const float*)d_in[24];
    const float* d1b2 = (const float*)d_in[25];
    const float* fw   = (const float*)d_in[26];
    const float* fb   = (const float*)d_in[27];
    const float* fcw  = (const float*)d_in[28];
    const float* fcb  = (const float*)d_in[29];

    // ---- workspace: WT(4MB) A(33.5) D(16.8) E(16.8) B(33.5) C(8.4) F(33.5)
    char* wsb = (char*)d_ws;
    char* WT = wsb;
    char* A  = wsb + 4194304;
    char* D  = A + 33554432;
    char* E  = D + 16777216;
    char* Bb = E + 16777216;
    char* C  = Bb + 33554432;
    char* F  = C + 8388608;
    float* fcwT   = (float*)(WT + 1179648);
    unsigned short* fw16 = (unsigned short*)(WT + 2097152);
    uint4* zp     = (uint4*)(WT + 4194304 - 8192);
    unsigned short* fpl = (unsigned short*)F;   // f NCHW fp16: 33.5 MB
    float* pooled = (float*)C;                  // 1.66 MB
    float* colsumG = (float*)(C + 2097152);     // 1.84 MB
    hipMemsetAsync(zp, 0, 8192, stream);

    // ---- merged weight transforms (1 launch) ----
    const float* wsrc[11] = {e1w2, e2w1, e2w2, bw1, bw2, u2w, d2w1, d2w2, u1w, d1w1, d1w2};
    const int wco[11] = {32, 64, 64, 128, 128, 64, 64, 64, 32, 32, 32};
    const int wci[11] = {32, 32, 64, 64, 128, 128, 128, 64, 64, 64, 32};
    size_t woff[11]; size_t o = 0;
    PrepArgs pa;
    unsigned eoff = 0;
    for (int i = 0; i < 11; ++i) {
        woff[i] = o; o += (size_t)wco[i] * wci[i] * 18;
        pa.src[i] = wsrc[i]; pa.dstOff[i] = (unsigned)woff[i];
        pa.Cout[i] = wco[i]; pa.Cin[i] = wci[i];
        pa.off[i] = eoff; eoff += (unsigned)(wco[i] * wci[i] * 9);
    }
    pa.src[11] = fcw; pa.dstOff[11] = 1179648; pa.Cout[11] = 0; pa.Cin[11] = 0;
    pa.off[11] = eoff; eoff += 49 * 512;
    pa.src[12] = fw; pa.dstOff[12] = 2097152; pa.Cout[12] = 0; pa.Cin[12] = 0;
    pa.off[12] = eoff; eoff += 4096;
    pa.off[13] = eoff;
    hipLaunchKernelGGL(prep_all_k, dim3((eoff + 255) / 256), dim3(256), 0, stream, pa, WT);
    auto WP = [&](int i) { return (const uint4*)(WT + woff[i]); };

    // CV1: 256² BM32 TW32 TH8 (39.25 KB, 4 blk/CU); CV2: 128² BM64 TW32 TH8
    // (58.6 KB, 2 blk/CU); CV3: 64² BM32 TW32 TH8. POOL variants fuse 2x2 maxpool.
    #define CV1(i1,C1,i2,C2,wi,bs,ot,Cout,up,rl,pl,po) \
        hipLaunchKernelGGL((convm4_k<32,32,8,8,up,pl>), dim3(8,32,8*((Cout)/32)), dim3(256), 0, stream, \
            (const uint4*)(i1), (C1)/8, (const uint4*)(i2), (C2)/8, WP(wi), bs, \
            (unsigned short*)(ot), Cout, rl, zp, (unsigned short*)(po))
    #define CV2(i1,C1,i2,C2,wi,bs,ot,Cout,up,rl,pl,po) \
        hipLaunchKernelGGL((convm4_k<64,32,8,7,up,pl>), dim3(4,16,8*((Cout)/64)), dim3(256), 0, stream, \
            (const uint4*)(i1), (C1)/8, (const uint4*)(i2), (C2)/8, WP(wi), bs, \
            (unsigned short*)(ot), Cout, rl, zp, (unsigned short*)(po))
    #define CV3(i1,C1,i2,C2,wi,bs,ot,Cout,up,rl) \
        hipLaunchKernelGGL((convm4_k<32,32,8,6,up,0>), dim3(2,8,8*((Cout)/32)), dim3(256), 0, stream, \
            (const uint4*)(i1), (C1)/8, (const uint4*)(i2), (C2)/8, WP(wi), bs, \
            (unsigned short*)(ot), Cout, rl, zp, (unsigned short*)nullptr)

    // encoder
    hipLaunchKernelGGL(conv0_k, dim3(16, 16, 32), dim3(16, 16), 0, stream,
                       x, e1w1, e1b1, (unsigned short*)A);        // e1a -> A
    CV1(A, 32, nullptr, 0, 0, e1b2, Bb, 32, 0, 1, 1, C);         // e1 -> B, p1 -> C (fused pool)
    CV2(C, 32, nullptr, 0, 1, e2b1, A, 64, 0, 1, 0, nullptr);    // e2a -> A
    CV2(A, 64, nullptr, 0, 2, e2b2, D, 64, 0, 1, 1, C);          // e2 -> D, p2 -> C (fused pool)
    // bottleneck
    CV3(C, 64, nullptr, 0, 3, bb1, E, 128, 0, 1);                // b1 -> E  (C free after)
    CV3(E, 128, nullptr, 0, 4, bb2, A, 128, 0, 1);               // b2 -> A
    // decoder level 2
    CV2(A, 128, nullptr, 0, 5, u2b, E, 64, 1, 1, 0, nullptr);    // u2 -> E (upsample)
    CV2(E, 64, D, 64, 6, d2b1, A, 64, 0, 1, 0, nullptr);         // d2a -> A (concat)
    CV2(A, 64, nullptr, 0, 7, d2b2, D, 64, 0, 1, 0, nullptr);    // d2 -> D
    // decoder level 1
    CV1(D, 64, nullptr, 0, 8, u1b, A, 32, 1, 1, 0, nullptr);     // u1 -> A (upsample)
    CV1(A, 32, Bb, 32, 9, d1b1, D, 32, 0, 1, 0, nullptr);        // d1a -> D+E (concat)
    CV1(D, 32, nullptr, 0, 10, d1b2, Bb, 32, 0, 1, 0, nullptr);  // d1 -> B
    // 1x1 conv (MFMA) -> NCHW fp16 planes
    hipLaunchKernelGGL(conv1x1f_k, dim3(256, 8), dim3(256), 0, stream,
                       (const uint4*)Bb, (const uint4*)fw16, fb, fpl);
    // pooling: global (2-pass, parallel over y-bins) + ROI (one wave each)
    hipLaunchKernelGGL(gcol_k, dim3(7, 32, 8), dim3(256), 0, stream, fpl, colsumG);
    hipLaunchKernelGGL(roi_k, dim3(1024, 8), dim3(64), 0, stream, fpl, rois, pooled);
    hipLaunchKernelGGL(gpool2_k, dim3(32, 8), dim3(64), 0, stream, colsumG, pooled);
    hipLaunchKernelGGL(fc_k, dim3(66, 8), dim3(512), 0, stream,
                       pooled, fcwT, fcb, (float*)d_out);
    #undef CV1
    #undef CV2
    #undef CV3
}